// Round 10
// baseline (1565.067 us; speedup 1.0000x reference)
//
#include <hip/hip_runtime.h>
#include <stdint.h>

#define SEQ  5120
#define DIMX 512
#define E2   2048
#define DI   1024
#define NST  16
#define DTR  32
#define KXP  64
#define LGS  2048
#define NSL  5
#define NSEG 8
#define SEGL 640

typedef unsigned short ushort_t;
typedef __attribute__((ext_vector_type(8))) __bf16 bf16x8;
typedef __attribute__((ext_vector_type(4))) float f32x4;

__device__ __forceinline__ float b2f(ushort_t u) {
  union { unsigned int i; float f; } v; v.i = ((unsigned int)u) << 16; return v.f;
}
__device__ __forceinline__ ushort_t f2b(float f) {
  union { float f; unsigned int i; } v; v.f = f;
  unsigned int u = v.i;
  return (ushort_t)((u + 0x7FFFu + ((u >> 16) & 1u)) >> 16);
}

#define AS1 __attribute__((address_space(1)))
#define AS3 __attribute__((address_space(3)))
__device__ __forceinline__ void glds16(const void* g, void* l) {
  __builtin_amdgcn_global_load_lds((const AS1 void*)g, (AS3 void*)l, 16, 0, 0);
}

__device__ __forceinline__ int pmap(int br, int t) {   // scan pos -> data pos
  return (br == 0) ? t : (br == 1) ? (SEQ - 1 - t) : ((t % NSL) * 1024 + t / NSL);
}
__device__ __forceinline__ int omap(int br, int t) {   // scan pos -> output pos
  return (br == 0) ? t : (br == 1) ? (SEQ - 1 - t) : ((t & 1023) * NSL + (t >> 10));
}

// ---------------- workspace layout (bytes) ------------------------------------
#define OFF_LWB   ((size_t)256)
#define OFF_LNGF  ((size_t)1280)
#define OFF_LNBF  ((size_t)3328)
#define OFF_LBF   ((size_t)5376)
#define OFF_CWF   ((size_t)5632)
#define OFF_CBF   ((size_t)54784)
#define OFF_DTBF  ((size_t)67072)
#define OFF_ALF   ((size_t)79360)
#define OFF_DDF   ((size_t)275968)
#define OFF_WEFF  ((size_t)288256)
#define OFF_SC    ((size_t)292352)
#define OFF_DTWB  ((size_t)333312)
#define OFF_XPWB  ((size_t)529920)
#define OFF_OPWB  ((size_t)923136)
#define OFF_INWB  ((size_t)1971712)
#define OFF_DTWF  ((size_t)4068864)     // 3*1024*32*4 = 393,216
#define OFF_XD    ((size_t)4462080)     // 6*5120*64*2 = 3,932,160
#define OFF_XZ    ((size_t)8394240)     // 2*5120*2048*2 = 41,943,040
// overlays inside dead-xz region (xz dead after conv+zg):
#define OFF_BF    ((size_t)8394240)     // 6*16*5120*4 = 1,966,080
#define OFF_CF    ((size_t)10360320)    // 1,966,080
#define OFF_HLOC  ((size_t)12326400)    // 3,145,728
#define OFF_HIN   ((size_t)15472128)    // 3,145,728
#define OFF_STOT  ((size_t)18617856)    // 196,608
#define OFF_UB    ((size_t)50337280)    // 6*5120*1024*2 = 62,914,560 (blocked)
#define OFF_H     OFF_UB                // ln-out h nested; dead before conv
#define OFF_ZGB   ((size_t)113251840)   // 2*64*5120*16*2 = 20,971,520 (blocked)
// total = 134,223,360 B (~128 MiB)

// ---------------- K0: batched import (f32 params -> ws, bf16 or f32) ----------
struct Ent { const void* s; void* d; int n; int fmt; };
struct Tab { Ent e[32]; };

__global__ __launch_bounds__(256) void k_import(Tab t, int cnt) {
  int id = blockIdx.y;
  if (id >= cnt) return;
  Ent E = t.e[id];
  int stride = gridDim.x * 256;
  const float* s = (const float*)E.s;
  if (E.fmt == 0) {
    ushort_t* dst = (ushort_t*)E.d;
    for (int i = blockIdx.x * 256 + threadIdx.x; i < E.n; i += stride) dst[i] = f2b(s[i]);
  } else {
    float* dst = (float*)E.d;
    for (int i = blockIdx.x * 256 + threadIdx.x; i < E.n; i += stride) dst[i] = s[i];
  }
}

// ---------------- K1: LayerNorm + ReLU -> h (bf16, both batches) --------------
__global__ __launch_bounds__(256) void k_ln(const float* __restrict__ x,
    const float* __restrict__ gam, const float* __restrict__ bet,
    ushort_t* __restrict__ h) {
  int token = blockIdx.x * 4 + (threadIdx.x >> 6);
  int lane = threadIdx.x & 63;
  const float* row = x + (size_t)token * DIMX + lane * 8;
  float4 a0 = *(const float4*)(row);
  float4 a1 = *(const float4*)(row + 4);
  float v[8] = {a0.x,a0.y,a0.z,a0.w,a1.x,a1.y,a1.z,a1.w};
  float s = 0.f, ss = 0.f;
#pragma unroll
  for (int i = 0; i < 8; i++) { s += v[i]; ss += v[i]*v[i]; }
#pragma unroll
  for (int m = 1; m < 64; m <<= 1) { s += __shfl_xor(s, m, 64); ss += __shfl_xor(ss, m, 64); }
  float mean = s * (1.f / DIMX);
  float rs = rsqrtf(ss * (1.f / DIMX) - mean * mean + 1e-5f);
  ushort_t o[8];
#pragma unroll
  for (int i = 0; i < 8; i++) {
    float y = (v[i] - mean) * rs * gam[lane*8+i] + bet[lane*8+i];
    o[i] = f2b(fmaxf(y, 0.f));
  }
  ushort_t* orow = h + (size_t)token * DIMX + lane * 8;
  *(ushort4*)(orow)     = make_ushort4(o[0],o[1],o[2],o[3]);
  *(ushort4*)(orow + 4) = make_ushort4(o[4],o[5],o[6],o[7]);
}

// ---------------- K2: in_proj GEMM (M=10240): xz[bl][e] = h @ W^T -------------
__global__ __launch_bounds__(256) void k_inproj(const ushort_t* __restrict__ hA,
    const ushort_t* __restrict__ Wb, ushort_t* __restrict__ xz) {
  __shared__ ushort_t As[128*32];
  __shared__ ushort_t Bs[128*32];
  const int tid = threadIdx.x;
  const int w = tid >> 6, lane = tid & 63;
  const int wr = w >> 1, wc = w & 1;
  const int m0 = blockIdx.x * 128, n0 = blockIdx.y * 128;
  const int lrow = lane & 15, lko = (lane >> 4) * 8;
  f32x4 acc[4][4];
#pragma unroll
  for (int i = 0; i < 4; i++)
#pragma unroll
    for (int j = 0; j < 4; j++) acc[i][j] = (f32x4){0.f,0.f,0.f,0.f};
  for (int k0 = 0; k0 < DIMX; k0 += 32) {
    __syncthreads();
#pragma unroll
    for (int r = 0; r < 2; r++) {
      int e = r * 256 + tid;
      int row = e >> 2, seg = e & 3;
      glds16(hA + (size_t)(m0 + row) * DIMX + k0 + seg * 8, &As[row*32 + seg*8]);
      glds16(Wb + (size_t)(n0 + row) * DIMX + k0 + seg * 8, &Bs[row*32 + seg*8]);
    }
    __syncthreads();
    bf16x8 aF[4], bF[4];
#pragma unroll
    for (int i = 0; i < 4; i++)
      aF[i] = *(const bf16x8*)&As[(wr*64 + i*16 + lrow)*32 + lko];
#pragma unroll
    for (int j = 0; j < 4; j++)
      bF[j] = *(const bf16x8*)&Bs[(wc*64 + j*16 + lrow)*32 + lko];
#pragma unroll
    for (int i = 0; i < 4; i++)
#pragma unroll
      for (int j = 0; j < 4; j++)
        acc[i][j] = __builtin_amdgcn_mfma_f32_16x16x32_bf16(aF[i], bF[j], acc[i][j], 0, 0, 0);
  }
#pragma unroll
  for (int i = 0; i < 4; i++)
#pragma unroll
    for (int j = 0; j < 4; j++)
#pragma unroll
      for (int r = 0; r < 4; r++) {
        int m = m0 + wr*64 + i*16 + (lane>>4)*4 + r;
        int n = n0 + wc*64 + j*16 + lrow;
        xz[(size_t)m * E2 + n] = f2b(acc[i][j][r]);
      }
}

// ---------------- K4: conv + silu -> uB[ch][d>>4][t][16] (blocked) ------------
__global__ __launch_bounds__(256) void k_conv(const ushort_t* __restrict__ xz,
    const float* __restrict__ cwA, const float* __restrict__ cbA,
    ushort_t* __restrict__ uB) {
  __shared__ ushort_t xs[67][64];
  int ch = blockIdx.z, br = ch >> 1, b = ch & 1;
  int t0 = blockIdx.x * 64, d0 = blockIdx.y * 64;
  int tid = threadIdx.x, col = tid & 63, rg = tid >> 6;
  const float* cw = cwA + (size_t)br * DI * 4;
  const float* cb = cbA + (size_t)br * DI;
#pragma unroll
  for (int i = 0; i < 17; i++) {
    int row = rg + i * 4;
    if (row < 67) {
      int tau = t0 - 3 + row;
      ushort_t val = 0;
      if (tau >= 0) val = xz[((size_t)b * SEQ + pmap(br, tau)) * E2 + d0 + col];
      xs[row][col] = val;
    }
  }
  __syncthreads();
  int d = d0 + col;
  float w0 = cw[d*4+0], w1 = cw[d*4+1], w2 = cw[d*4+2], w3 = cw[d*4+3];
  float bias = cb[d];
  size_t dbbase = ((size_t)(ch * 64 + (d >> 4))) * SEQ;
#pragma unroll
  for (int i = 0; i < 16; i++) {
    int ti = rg + i * 4;
    float a = bias + w0*b2f(xs[ti][col]) + w1*b2f(xs[ti+1][col])
                   + w2*b2f(xs[ti+2][col]) + w3*b2f(xs[ti+3][col]);
    float val = a / (1.f + __expf(-a));
    uB[(dbbase + t0 + ti) * 16 + (col & 15)] = f2b(val);
  }
}

// ---------------- K4b: gate precompute -> zgB[b][d>>4][l][16] (blocked) -------
__global__ __launch_bounds__(256) void k_zg(const ushort_t* __restrict__ xz,
    const float* __restrict__ weff, ushort_t* __restrict__ zgB) {
  int b = blockIdx.z;
  int l0 = blockIdx.x * 64, d0 = blockIdx.y * 64;
  int tid = threadIdx.x, col = tid & 63, rg = tid >> 6;
  int d = d0 + col;
  float wef = weff[d];
  size_t dbbase = ((size_t)(b * 64 + (d >> 4))) * SEQ;
#pragma unroll
  for (int i = 0; i < 16; i++) {
    int l = l0 + rg + i * 4;
    float zr = b2f(xz[((size_t)b * SEQ + l) * E2 + DI + d]);
    float z = zr / (1.f + __expf(-zr));
    zgB[(dbbase + l) * 16 + (col & 15)] = f2b(z * wef);
  }
}

// ---------------- K5: x_dbl GEMM (reads blocked uB): xd[ch][t][64] ------------
__global__ __launch_bounds__(256) void k_xdbl(const ushort_t* __restrict__ uB,
    const ushort_t* __restrict__ xpwA, ushort_t* __restrict__ xdA) {
  __shared__ ushort_t As[64*32];
  __shared__ ushort_t Bs[64*32];
  int ch = blockIdx.y, br = ch >> 1;
  const ushort_t* xpw = xpwA + (size_t)br * KXP * DI;
  ushort_t* xd = xdA + (size_t)ch * SEQ * KXP;
  int t0 = blockIdx.x * 64;
  int tid = threadIdx.x, w = tid >> 6, lane = tid & 63;
  int lrow = lane & 15, lko = (lane >> 4) * 8;
  int row = tid >> 2, seg = tid & 3;
  f32x4 acc[4];
#pragma unroll
  for (int j = 0; j < 4; j++) acc[j] = (f32x4){0.f,0.f,0.f,0.f};
  for (int k0 = 0; k0 < DI; k0 += 32) {
    __syncthreads();
    glds16(uB + (((size_t)(ch*64 + (k0>>4) + (seg>>1)) * SEQ + t0 + row) * 16 + (seg&1)*8),
           &As[row*32 + seg*8]);
    glds16(xpw + (size_t)row * DI + k0 + seg * 8, &Bs[row*32 + seg*8]);
    __syncthreads();
    bf16x8 aF = *(const bf16x8*)&As[(w*16 + lrow)*32 + lko];
#pragma unroll
    for (int j = 0; j < 4; j++) {
      bf16x8 bF = *(const bf16x8*)&Bs[(j*16 + lrow)*32 + lko];
      acc[j] = __builtin_amdgcn_mfma_f32_16x16x32_bf16(aF, bF, acc[j], 0, 0, 0);
    }
  }
#pragma unroll
  for (int j = 0; j < 4; j++)
#pragma unroll
    for (int r = 0; r < 4; r++) {
      int t = t0 + w*16 + (lane>>4)*4 + r;
      xd[(size_t)t * KXP + j*16 + lrow] = f2b(acc[j][r]);
    }
}

// ---------------- K5b: expand xd B/C -> Bf/Cf[ch][n][t] f32 -------------------
__global__ __launch_bounds__(256) void k_bc(const ushort_t* __restrict__ xdA,
    float* __restrict__ Bf, float* __restrict__ Cf) {
  __shared__ float tb[128][34];
  int ch = blockIdx.y, t0 = blockIdx.x * 128;
  int tid = threadIdx.x;
  const ushort_t* xdb = xdA + (size_t)ch * SEQ * KXP;
#pragma unroll
  for (int i = 0; i < 2; i++) {
    int r = (tid >> 2) + i * 64;
    int q = tid & 3;
    const ushort_t* p = xdb + (size_t)(t0 + r) * KXP + 32 + q * 8;
    uint4 v = *(const uint4*)p;
    unsigned int wd[4] = {v.x, v.y, v.z, v.w};
    float* dst = &tb[r][q * 8];
#pragma unroll
    for (int j = 0; j < 4; j++) {
      dst[2*j]   = __uint_as_float(wd[j] << 16);
      dst[2*j+1] = __uint_as_float(wd[j] & 0xFFFF0000u);
    }
  }
  __syncthreads();
  int nn = tid >> 4, sg = tid & 15;
  float ob[8], oc[8];
#pragma unroll
  for (int j = 0; j < 8; j++) {
    ob[j] = tb[sg*8 + j][nn];
    oc[j] = tb[sg*8 + j][16 + nn];
  }
  float* Bp = Bf + ((size_t)ch * NST + nn) * SEQ + t0 + sg * 8;
  float* Cp = Cf + ((size_t)ch * NST + nn) * SEQ + t0 + sg * 8;
  *(float4*)Bp       = make_float4(ob[0],ob[1],ob[2],ob[3]);
  *(float4*)(Bp + 4) = make_float4(ob[4],ob[5],ob[6],ob[7]);
  *(float4*)Cp       = make_float4(oc[0],oc[1],oc[2],oc[3]);
  *(float4*)(Cp + 4) = make_float4(oc[4],oc[5],oc[6],oc[7]);
}

// ---------------- K7a: segmented local scan (lean-LDS version) ----------------
// grid 3072 = ch(bid>>9) x seg((bid>>6)&7) x dblk(bid&63)
__global__ __launch_bounds__(256, 4) void k_scan1(
    const ushort_t* __restrict__ xdA, const ushort_t* __restrict__ uB,
    const ushort_t* __restrict__ zgB, const float* __restrict__ Bf,
    const float* __restrict__ Cf, const float* __restrict__ dtwf,
    const float* __restrict__ dtbf, const float* __restrict__ alf,
    const float* __restrict__ ddf, float* __restrict__ sc,
    float* __restrict__ Hloc, float* __restrict__ Stot) {
  __shared__ __align__(16) float BS[4][16][18];
  __shared__ __align__(16) float CS[4][16][18];
  __shared__ float2 ddS[4][4][17];
  int bid = blockIdx.x;
  int dblk = bid & 63, seg = (bid >> 6) & 7, ch = bid >> 9;
  int br = ch >> 1, b = ch & 1;
  int tid = threadIdx.x, w = tid >> 6, lane = tid & 63, g = lane >> 4, n = lane & 15;
  int dloc = w * 4 + g;
  int d = dblk * 16 + dloc;
  float dtb_d = dtbf[br * DI + d];
  float Ap  = -__expf(alf[br * (DI*NST) + d * NST + n]);
  float Dd  = ddf[br * DI + d];
  const float* dwrow = dtwf + ((size_t)br * DI + d) * DTR;
  const ushort_t* xdb = xdA + (size_t)ch * SEQ * KXP;
  const ushort_t* uBp = uB  + ((size_t)(ch * 64 + dblk) * SEQ) * 16;
  const ushort_t* zgp = zgB + ((size_t)(b  * 64 + dblk) * SEQ) * 16;
  const float* Bfp = Bf + ((size_t)ch * NST) * SEQ;
  const float* Cfp = Cf + ((size_t)ch * NST) * SEQ;
  float* srow = sc + (size_t)b * SEQ;
  float hst = 0.f, Sacc = 0.f;
  int sn = lane >> 2, sq = lane & 3;
  for (int t0 = seg * SEGL; t0 < seg * SEGL + SEGL; t0 += 16) {
    *(float4*)&BS[w][sn][sq*4] = *(const float4*)&Bfp[(size_t)sn * SEQ + t0 + sq*4];
    *(float4*)&CS[w][sn][sq*4] = *(const float4*)&Cfp[(size_t)sn * SEQ + t0 + sq*4];
    const ushort_t* rp = xdb + (size_t)(t0 + n) * KXP;
    uint4 q0 = *(const uint4*)(rp),      q1 = *(const uint4*)(rp + 8);
    uint4 q2 = *(const uint4*)(rp + 16), q3 = *(const uint4*)(rp + 24);
    float acc = dtb_d;
    {
      unsigned int wds[16] = {q0.x,q0.y,q0.z,q0.w, q1.x,q1.y,q1.z,q1.w,
                              q2.x,q2.y,q2.z,q2.w, q3.x,q3.y,q3.z,q3.w};
#pragma unroll
      for (int jj = 0; jj < 8; jj++) {
        float4 wv = *(const float4*)&dwrow[jj * 4];
        acc = fmaf(__uint_as_float(wds[2*jj]   << 16),         wv.x, acc);
        acc = fmaf(__uint_as_float(wds[2*jj]   & 0xFFFF0000u), wv.y, acc);
        acc = fmaf(__uint_as_float(wds[2*jj+1] << 16),         wv.z, acc);
        acc = fmaf(__uint_as_float(wds[2*jj+1] & 0xFFFF0000u), wv.w, acc);
      }
    }
    float dlt = (acc > 20.f) ? acc : log1pf(__expf(acc));
    Sacc += dlt;
    float u    = b2f(uBp[(size_t)(t0 + n) * 16 + dloc]);
    float gate = b2f(zgp[(size_t)pmap(br, t0 + n) * 16 + dloc]);
    float du  = dlt * u;
    float dug = Dd * u * gate;
    ddS[w][g][n] = make_float2(dlt, du);
    float Bk[16], Ck[16];
#pragma unroll
    for (int j = 0; j < 4; j++) {
      *(float4*)&Bk[j*4] = *(const float4*)&BS[w][n][j*4];
      *(float4*)&Ck[j*4] = *(const float4*)&CS[w][n][j*4];
    }
    float hC[16];
#pragma unroll
    for (int k = 0; k < 16; k++) {
      float2 v = ddS[w][g][k];
      hst = fmaf(__expf(v.x * Ap), hst, v.y * Bk[k]);
      hC[k] = hst * Ck[k];
    }
    float a8[8], a4[4], a2[2], y;
#pragma unroll
    for (int j = 0; j < 8; j++) {
      float keep = (n & 8) ? hC[j+8] : hC[j];
      float send = (n & 8) ? hC[j]   : hC[j+8];
      a8[j] = keep + __shfl_xor(send, 8, 64);
    }
#pragma unroll
    for (int j = 0; j < 4; j++) {
      float keep = (n & 4) ? a8[j+4] : a8[j];
      float send = (n & 4) ? a8[j]   : a8[j+4];
      a4[j] = keep + __shfl_xor(send, 4, 64);
    }
#pragma unroll
    for (int j = 0; j < 2; j++) {
      float keep = (n & 2) ? a4[j+2] : a4[j];
      float send = (n & 2) ? a4[j]   : a4[j+2];
      a2[j] = keep + __shfl_xor(send, 2, 64);
    }
    {
      float keep = (n & 1) ? a2[1] : a2[0];
      float send = (n & 1) ? a2[0] : a2[1];
      y = keep + __shfl_xor(send, 1, 64);
    }
    y = fmaf(y, gate, dug);
    y += __shfl_xor(y, 16, 64);
    y += __shfl_xor(y, 32, 64);
    if (lane < 16) atomicAdd(srow + omap(br, t0 + lane), y);
  }
  Hloc[(((size_t)ch * NSEG + seg) * 1024 + d) * 16 + n] = hst;
  Sacc += __shfl_xor(Sacc, 1, 64);
  Sacc += __shfl_xor(Sacc, 2, 64);
  Sacc += __shfl_xor(Sacc, 4, 64);
  Sacc += __shfl_xor(Sacc, 8, 64);
  if (n == 0) Stot[((size_t)ch * NSEG + seg) * 1024 + d] = Sacc;
}

// ---------------- K7b: stitch segment states ----------------------------------
__global__ __launch_bounds__(256) void k_stitch(const float* __restrict__ Stot,
    const float* __restrict__ Hloc, const float* __restrict__ alf,
    float* __restrict__ Hin) {
  int idx = blockIdx.x * 256 + threadIdx.x;     // 98304 = 6*1024*16
  int ch = idx >> 14, rem = idx & 16383, d = rem >> 4, n = rem & 15;
  int br = ch >> 1;
  float A = -__expf(alf[(size_t)br * (DI*NST) + d * NST + n]);
  float h = 0.f;
  for (int s = 0; s < NSEG; s++) {
    size_t base = ((size_t)ch * NSEG + s) * 1024 + d;
    Hin[base * 16 + n] = h;
    h = __expf(A * Stot[base]) * h + Hloc[base * 16 + n];
  }
}

// ---------------- K7c: carry correction (parallel over t AND seg) -------------
// grid (256 cg, 7 seg-1, 6 ch). wave w -> channel d = cg*4+w.
__global__ __launch_bounds__(256, 6) void k_scan2(
    const ushort_t* __restrict__ zgB, const ushort_t* __restrict__ xdA,
    const ushort_t* __restrict__ dtwb, const float* __restrict__ dtbf,
    const float* __restrict__ alf, const float* __restrict__ Hin,
    float* __restrict__ sc) {
  __shared__ float red[4][72];
  int cg = blockIdx.x, seg = blockIdx.y + 1, ch = blockIdx.z;
  int br = ch >> 1, b = ch & 1;
  int tid = threadIdx.x, w = tid >> 6, lane = tid & 63;
  int d = cg * 4 + w;
  const ushort_t* dwp = dtwb + (size_t)br * (DI*DTR) + (size_t)d * DTR;
  uint4 dq0 = *(const uint4*)(dwp), dq1 = *(const uint4*)(dwp + 8),
        dq2 = *(const uint4*)(dwp + 16), dq3 = *(const uint4*)(dwp + 24);
  float dw[32];
  {
    unsigned int wds[16] = {dq0.x,dq0.y,dq0.z,dq0.w, dq1.x,dq1.y,dq1.z,dq1.w,
                            dq2.x,dq2.y,dq2.z,dq2.w, dq3.x,dq3.y,dq3.z,dq3.w};
#pragma unroll
    for (int j = 0; j < 16; j++) {
      dw[2*j]   = __uint_as_float(wds[j] << 16);
      dw[2*j+1] = __uint_as_float(wds[j] & 0xFFFF0000u);
    }
  }
  float dtb_d = dtbf[br * DI + d];
  float A_[16];
#pragma unroll
  for (int nn = 0; nn < 16; nn++)
    A_[nn] = -__expf(alf[(size_t)br * (DI*NST) + d * NST + nn]);
  const ushort_t* xdb = xdA + (size_t)ch * SEQ * KXP;
  const ushort_t* zgp = zgB + ((size_t)(b * 64 + (d >> 4)) * SEQ) * 16;
  int dsub = d & 15;
  float* srow = sc + (size_t)b * SEQ;
  float Hn[16];
  const float* hp = Hin + (((size_t)ch * NSEG + seg) * 1024 + d) * 16;
#pragma unroll
  for (int nn = 0; nn < 16; nn++) Hn[nn] = hp[nn];
  float carry = 0.f;
  for (int w0 = seg * SEGL; w0 < seg * SEGL + SEGL; w0 += 64) {
    int t = w0 + lane;
    const ushort_t* rp = xdb + (size_t)t * KXP;
    uint4 q0 = *(const uint4*)(rp),      q1 = *(const uint4*)(rp + 8),
          q2 = *(const uint4*)(rp + 16), q3 = *(const uint4*)(rp + 24);
    uint4 c0 = *(const uint4*)(rp + 48), c1 = *(const uint4*)(rp + 56);
    float acc = dtb_d;
    {
      unsigned int wds[16] = {q0.x,q0.y,q0.z,q0.w, q1.x,q1.y,q1.z,q1.w,
                              q2.x,q2.y,q2.z,q2.w, q3.x,q3.y,q3.z,q3.w};
#pragma unroll
      for (int j = 0; j < 16; j++) {
        acc = fmaf(__uint_as_float(wds[j] << 16),         dw[2*j],   acc);
        acc = fmaf(__uint_as_float(wds[j] & 0xFFFF0000u), dw[2*j+1], acc);
      }
    }
    float dlt = (acc > 20.f) ? acc : log1pf(__expf(acc));
    float S = dlt;
#pragma unroll
    for (int ofs = 1; ofs < 64; ofs <<= 1) {
      float v = __shfl_up(S, ofs, 64);
      if (lane >= ofs) S += v;
    }
    float tot = __shfl(S, 63, 64);
    S += carry; carry += tot;
    float corr = 0.f;
    {
      unsigned int cws[8] = {c0.x,c0.y,c0.z,c0.w, c1.x,c1.y,c1.z,c1.w};
#pragma unroll
      for (int j = 0; j < 8; j++) {
        float Ca = __uint_as_float(cws[j] << 16);
        float Cb = __uint_as_float(cws[j] & 0xFFFF0000u);
        corr = fmaf(Ca * Hn[2*j],   __expf(A_[2*j]   * S), corr);
        corr = fmaf(Cb * Hn[2*j+1], __expf(A_[2*j+1] * S), corr);
      }
    }
    float gate = b2f(zgp[(size_t)pmap(br, t) * 16 + dsub]);
    float y = corr * gate;
    red[w][lane] = y;
    __syncthreads();
    if (w == 0) {
      float ytot = red[0][lane] + red[1][lane] + red[2][lane] + red[3][lane];
      atomicAdd(srow + omap(br, t), ytot);
    }
    __syncthreads();
  }
}

// ---------------- K8: w_eff[d] = lin_w . out_proj_w[:,d]; zero score_acc ------
__global__ __launch_bounds__(256) void k_weff_init(const ushort_t* __restrict__ opwb,
    const ushort_t* __restrict__ lwb, float* __restrict__ weff, float* __restrict__ sc) {
  int i = blockIdx.x * 256 + threadIdx.x;
  if (i < DI) {
    float s = 0.f;
    for (int o = 0; o < DIMX; o++) s += b2f(lwb[o]) * b2f(opwb[(size_t)o * DI + i]);
    weff[i] = s;
  }
  int j = i - DI;
  if (j >= 0 && j < 2 * SEQ) sc[j] = 0.f;
}

// ---------------- K9: outputs (f32): group interp+sigmoid, individual ---------
__global__ __launch_bounds__(256) void k_out(const float* __restrict__ g0,
    const float* __restrict__ g1, const float* __restrict__ g2,
    const float* __restrict__ sc, const float* __restrict__ lbf,
    float* __restrict__ out) {
  int idx = blockIdx.x * 256 + threadIdx.x;
  if (idx < 3 * SEQ) {
    int j = idx / SEQ, t = idx % SEQ;
    const float* g = (j == 0) ? g0 : (j == 1) ? g1 : g2;
    float pos = t * ((float)(LGS - 1) / (float)(SEQ - 1));
    int i0 = (int)floorf(pos);
    if (i0 < 0) i0 = 0; if (i0 > LGS - 2) i0 = LGS - 2;
    float wt = pos - (float)i0;
    float v = g[i0] * (1.f - wt) + g[i0 + 1] * wt;
    out[idx] = 1.f / (1.f + __expf(-v));
  } else if (idx < 5 * SEQ) {
    float t = sc[idx - 3 * SEQ] + lbf[0];
    out[idx] = 1.f / (1.f + __expf(-t));
  }
}

extern "C" void kernel_launch(void* const* d_in, const int* in_sizes, int n_in,
                              void* d_out, int out_size, void* d_ws, size_t ws_size,
                              hipStream_t stream) {
  char* ws = (char*)d_ws;
  ushort_t* lwb   = (ushort_t*)(ws + OFF_LWB);
  float*    lngf  = (float*)(ws + OFF_LNGF);
  float*    lnbf  = (float*)(ws + OFF_LNBF);
  float*    lbf   = (float*)(ws + OFF_LBF);
  float*    cwf   = (float*)(ws + OFF_CWF);
  float*    cbf   = (float*)(ws + OFF_CBF);
  float*    dtbf  = (float*)(ws + OFF_DTBF);
  float*    alf   = (float*)(ws + OFF_ALF);
  float*    ddf   = (float*)(ws + OFF_DDF);
  float*    weff  = (float*)(ws + OFF_WEFF);
  float*    sc    = (float*)(ws + OFF_SC);
  ushort_t* dtwb  = (ushort_t*)(ws + OFF_DTWB);
  float*    dtwf  = (float*)(ws + OFF_DTWF);
  ushort_t* xpwb  = (ushort_t*)(ws + OFF_XPWB);
  ushort_t* opwb  = (ushort_t*)(ws + OFF_OPWB);
  ushort_t* inwb  = (ushort_t*)(ws + OFF_INWB);
  ushort_t* xd    = (ushort_t*)(ws + OFF_XD);
  ushort_t* xz    = (ushort_t*)(ws + OFF_XZ);
  float*    Bf    = (float*)(ws + OFF_BF);
  float*    Cf    = (float*)(ws + OFF_CF);
  ushort_t* uB    = (ushort_t*)(ws + OFF_UB);
  ushort_t* h     = (ushort_t*)(ws + OFF_H);
  ushort_t* zgB   = (ushort_t*)(ws + OFF_ZGB);
  float*    Hloc  = (float*)(ws + OFF_HLOC);
  float*    Hin   = (float*)(ws + OFF_HIN);
  float*    Stot  = (float*)(ws + OFF_STOT);
  float*    OUT   = (float*)d_out;

  Tab tab;
  int c = 0;
  tab.e[c++] = {d_in[3], inwb, E2 * DIMX, 0};
  tab.e[c++] = {d_in[4], opwb, DIMX * DI, 0};
  tab.e[c++] = {d_in[5], lwb, DIMX, 0};
  for (int br = 0; br < 3; br++) {
    int base = 10 + br * 7;
    tab.e[c++] = {d_in[base + 2], xpwb + (size_t)br * KXP * DI, KXP * DI, 0};
    tab.e[c++] = {d_in[base + 3], dtwb + (size_t)br * DI * DTR, DI * DTR, 0};
    tab.e[c++] = {d_in[base + 3], dtwf + (size_t)br * DI * DTR, DI * DTR, 1};
  }
  tab.e[c++] = {d_in[1], lngf, DIMX, 1};
  tab.e[c++] = {d_in[2], lnbf, DIMX, 1};
  tab.e[c++] = {d_in[6], lbf, 1, 1};
  for (int br = 0; br < 3; br++) {
    int base = 10 + br * 7;
    tab.e[c++] = {d_in[base + 0], cwf + (size_t)br * DI * 4, DI * 4, 1};
    tab.e[c++] = {d_in[base + 1], cbf + (size_t)br * DI, DI, 1};
    tab.e[c++] = {d_in[base + 4], dtbf + (size_t)br * DI, DI, 1};
    tab.e[c++] = {d_in[base + 5], alf + (size_t)br * DI * NST, DI * NST, 1};
    tab.e[c++] = {d_in[base + 6], ddf + (size_t)br * DI, DI, 1};
  }

  dim3 blk(256);
  k_import<<<dim3(64, c), blk, 0, stream>>>(tab, c);
  k_weff_init<<<44, blk, 0, stream>>>(opwb, lwb, weff, sc);
  k_ln<<<2560, blk, 0, stream>>>((const float*)d_in[0], lngf, lnbf, h);
  k_inproj<<<dim3(80, 16), blk, 0, stream>>>(h, inwb, xz);
  k_conv<<<dim3(80, 16, 6), blk, 0, stream>>>(xz, cwf, cbf, uB);
  k_zg<<<dim3(80, 16, 2), blk, 0, stream>>>(xz, weff, zgB);
  k_xdbl<<<dim3(80, 6), blk, 0, stream>>>(uB, xpwb, xd);
  k_bc<<<dim3(40, 6), blk, 0, stream>>>(xd, Bf, Cf);
  k_scan1<<<3072, blk, 0, stream>>>(xd, uB, zgB, Bf, Cf, dtwf, dtbf, alf, ddf,
                                    sc, Hloc, Stot);
  k_stitch<<<384, blk, 0, stream>>>(Stot, Hloc, alf, Hin);
  k_scan2<<<dim3(256, NSEG - 1, 6), blk, 0, stream>>>(zgB, xd, dtwb, dtbf, alf,
                                                      Hin, sc);
  k_out<<<100, blk, 0, stream>>>((const float*)d_in[7], (const float*)d_in[8],
                                 (const float*)d_in[9], sc, lbf, OUT);
}

// Round 11
// 850.985 us; speedup vs baseline: 1.8391x; 1.8391x over previous
//
#include <hip/hip_runtime.h>
#include <stdint.h>

#define SEQ  5120
#define DIMX 512
#define E2   2048
#define DI   1024
#define NST  16
#define DTR  32
#define KXP  64
#define LGS  2048
#define NSL  5
#define NSEG 8
#define SEGL 640

typedef unsigned short ushort_t;
typedef __attribute__((ext_vector_type(8))) __bf16 bf16x8;
typedef __attribute__((ext_vector_type(4))) float f32x4;

__device__ __forceinline__ float b2f(ushort_t u) {
  union { unsigned int i; float f; } v; v.i = ((unsigned int)u) << 16; return v.f;
}
__device__ __forceinline__ ushort_t f2b(float f) {
  union { float f; unsigned int i; } v; v.f = f;
  unsigned int u = v.i;
  return (ushort_t)((u + 0x7FFFu + ((u >> 16) & 1u)) >> 16);
}

#define AS1 __attribute__((address_space(1)))
#define AS3 __attribute__((address_space(3)))
__device__ __forceinline__ void glds16(const void* g, void* l) {
  __builtin_amdgcn_global_load_lds((const AS1 void*)g, (AS3 void*)l, 16, 0, 0);
}

__device__ __forceinline__ int pmap(int br, int t) {   // scan pos -> data pos
  return (br == 0) ? t : (br == 1) ? (SEQ - 1 - t) : ((t % NSL) * 1024 + t / NSL);
}
__device__ __forceinline__ int omap(int br, int t) {   // scan pos -> output pos
  return (br == 0) ? t : (br == 1) ? (SEQ - 1 - t) : ((t & 1023) * NSL + (t >> 10));
}

// ---------------- workspace layout (bytes) ------------------------------------
#define OFF_LWB   ((size_t)256)
#define OFF_LNGF  ((size_t)1280)
#define OFF_LNBF  ((size_t)3328)
#define OFF_LBF   ((size_t)5376)
#define OFF_CWF   ((size_t)5632)
#define OFF_CBF   ((size_t)54784)
#define OFF_DTBF  ((size_t)67072)
#define OFF_ALF   ((size_t)79360)
#define OFF_DDF   ((size_t)275968)
#define OFF_WEFF  ((size_t)288256)
#define OFF_SC    ((size_t)292352)
#define OFF_DTWB  ((size_t)333312)
#define OFF_XPWB  ((size_t)529920)
#define OFF_OPWB  ((size_t)923136)
#define OFF_INWB  ((size_t)1971712)
#define OFF_DTWF  ((size_t)4068864)     // 3*1024*32*4 = 393,216
#define OFF_XD    ((size_t)4462080)     // 6*5120*64*2 = 3,932,160
#define OFF_XZ    ((size_t)8394240)     // 2*5120*2048*2 = 41,943,040
// overlays inside dead-xz region (xz dead after conv+zg):
#define OFF_BF    ((size_t)8394240)     // 6*16*5120*4 = 1,966,080
#define OFF_CF    ((size_t)10360320)    // 1,966,080
#define OFF_HLOC  ((size_t)12326400)    // 3,145,728
#define OFF_HIN   ((size_t)15472128)    // 3,145,728
#define OFF_STOT  ((size_t)18617856)    // 196,608
#define OFF_UB    ((size_t)50337280)    // 6*5120*1024*2 = 62,914,560 (blocked; dlt after scan1)
#define OFF_H     OFF_UB                // ln-out h nested; dead before conv
#define OFF_ZGB   ((size_t)113251840)   // 2*64*5120*16*2 = 20,971,520 (blocked)
// total = 134,223,360 B (~128 MiB)

// ---------------- K0: batched import (f32 params -> ws, bf16 or f32) ----------
struct Ent { const void* s; void* d; int n; int fmt; };
struct Tab { Ent e[32]; };

__global__ __launch_bounds__(256) void k_import(Tab t, int cnt) {
  int id = blockIdx.y;
  if (id >= cnt) return;
  Ent E = t.e[id];
  int stride = gridDim.x * 256;
  const float* s = (const float*)E.s;
  if (E.fmt == 0) {
    ushort_t* dst = (ushort_t*)E.d;
    for (int i = blockIdx.x * 256 + threadIdx.x; i < E.n; i += stride) dst[i] = f2b(s[i]);
  } else {
    float* dst = (float*)E.d;
    for (int i = blockIdx.x * 256 + threadIdx.x; i < E.n; i += stride) dst[i] = s[i];
  }
}

// ---------------- K1: LayerNorm + ReLU -> h (bf16, both batches) --------------
__global__ __launch_bounds__(256) void k_ln(const float* __restrict__ x,
    const float* __restrict__ gam, const float* __restrict__ bet,
    ushort_t* __restrict__ h) {
  int token = blockIdx.x * 4 + (threadIdx.x >> 6);
  int lane = threadIdx.x & 63;
  const float* row = x + (size_t)token * DIMX + lane * 8;
  float4 a0 = *(const float4*)(row);
  float4 a1 = *(const float4*)(row + 4);
  float v[8] = {a0.x,a0.y,a0.z,a0.w,a1.x,a1.y,a1.z,a1.w};
  float s = 0.f, ss = 0.f;
#pragma unroll
  for (int i = 0; i < 8; i++) { s += v[i]; ss += v[i]*v[i]; }
#pragma unroll
  for (int m = 1; m < 64; m <<= 1) { s += __shfl_xor(s, m, 64); ss += __shfl_xor(ss, m, 64); }
  float mean = s * (1.f / DIMX);
  float rs = rsqrtf(ss * (1.f / DIMX) - mean * mean + 1e-5f);
  ushort_t o[8];
#pragma unroll
  for (int i = 0; i < 8; i++) {
    float y = (v[i] - mean) * rs * gam[lane*8+i] + bet[lane*8+i];
    o[i] = f2b(fmaxf(y, 0.f));
  }
  ushort_t* orow = h + (size_t)token * DIMX + lane * 8;
  *(ushort4*)(orow)     = make_ushort4(o[0],o[1],o[2],o[3]);
  *(ushort4*)(orow + 4) = make_ushort4(o[4],o[5],o[6],o[7]);
}

// ---------------- K2: in_proj GEMM (M=10240): xz[bl][e] = h @ W^T -------------
__global__ __launch_bounds__(256) void k_inproj(const ushort_t* __restrict__ hA,
    const ushort_t* __restrict__ Wb, ushort_t* __restrict__ xz) {
  __shared__ ushort_t As[128*32];
  __shared__ ushort_t Bs[128*32];
  const int tid = threadIdx.x;
  const int w = tid >> 6, lane = tid & 63;
  const int wr = w >> 1, wc = w & 1;
  const int m0 = blockIdx.x * 128, n0 = blockIdx.y * 128;
  const int lrow = lane & 15, lko = (lane >> 4) * 8;
  f32x4 acc[4][4];
#pragma unroll
  for (int i = 0; i < 4; i++)
#pragma unroll
    for (int j = 0; j < 4; j++) acc[i][j] = (f32x4){0.f,0.f,0.f,0.f};
  for (int k0 = 0; k0 < DIMX; k0 += 32) {
    __syncthreads();
#pragma unroll
    for (int r = 0; r < 2; r++) {
      int e = r * 256 + tid;
      int row = e >> 2, seg = e & 3;
      glds16(hA + (size_t)(m0 + row) * DIMX + k0 + seg * 8, &As[row*32 + seg*8]);
      glds16(Wb + (size_t)(n0 + row) * DIMX + k0 + seg * 8, &Bs[row*32 + seg*8]);
    }
    __syncthreads();
    bf16x8 aF[4], bF[4];
#pragma unroll
    for (int i = 0; i < 4; i++)
      aF[i] = *(const bf16x8*)&As[(wr*64 + i*16 + lrow)*32 + lko];
#pragma unroll
    for (int j = 0; j < 4; j++)
      bF[j] = *(const bf16x8*)&Bs[(wc*64 + j*16 + lrow)*32 + lko];
#pragma unroll
    for (int i = 0; i < 4; i++)
#pragma unroll
      for (int j = 0; j < 4; j++)
        acc[i][j] = __builtin_amdgcn_mfma_f32_16x16x32_bf16(aF[i], bF[j], acc[i][j], 0, 0, 0);
  }
#pragma unroll
  for (int i = 0; i < 4; i++)
#pragma unroll
    for (int j = 0; j < 4; j++)
#pragma unroll
      for (int r = 0; r < 4; r++) {
        int m = m0 + wr*64 + i*16 + (lane>>4)*4 + r;
        int n = n0 + wc*64 + j*16 + lrow;
        xz[(size_t)m * E2 + n] = f2b(acc[i][j][r]);
      }
}

// ---------------- K4: conv + silu -> uB[ch][d>>4][t][16] (blocked) ------------
__global__ __launch_bounds__(256) void k_conv(const ushort_t* __restrict__ xz,
    const float* __restrict__ cwA, const float* __restrict__ cbA,
    ushort_t* __restrict__ uB) {
  __shared__ ushort_t xs[67][64];
  int ch = blockIdx.z, br = ch >> 1, b = ch & 1;
  int t0 = blockIdx.x * 64, d0 = blockIdx.y * 64;
  int tid = threadIdx.x, col = tid & 63, rg = tid >> 6;
  const float* cw = cwA + (size_t)br * DI * 4;
  const float* cb = cbA + (size_t)br * DI;
#pragma unroll
  for (int i = 0; i < 17; i++) {
    int row = rg + i * 4;
    if (row < 67) {
      int tau = t0 - 3 + row;
      ushort_t val = 0;
      if (tau >= 0) val = xz[((size_t)b * SEQ + pmap(br, tau)) * E2 + d0 + col];
      xs[row][col] = val;
    }
  }
  __syncthreads();
  int d = d0 + col;
  float w0 = cw[d*4+0], w1 = cw[d*4+1], w2 = cw[d*4+2], w3 = cw[d*4+3];
  float bias = cb[d];
  size_t dbbase = ((size_t)(ch * 64 + (d >> 4))) * SEQ;
#pragma unroll
  for (int i = 0; i < 16; i++) {
    int ti = rg + i * 4;
    float a = bias + w0*b2f(xs[ti][col]) + w1*b2f(xs[ti+1][col])
                   + w2*b2f(xs[ti+2][col]) + w3*b2f(xs[ti+3][col]);
    float val = a / (1.f + __expf(-a));
    uB[(dbbase + t0 + ti) * 16 + (col & 15)] = f2b(val);
  }
}

// ---------------- K4b: gate precompute -> zgB[b][d>>4][l][16] (blocked) -------
__global__ __launch_bounds__(256) void k_zg(const ushort_t* __restrict__ xz,
    const float* __restrict__ weff, ushort_t* __restrict__ zgB) {
  int b = blockIdx.z;
  int l0 = blockIdx.x * 64, d0 = blockIdx.y * 64;
  int tid = threadIdx.x, col = tid & 63, rg = tid >> 6;
  int d = d0 + col;
  float wef = weff[d];
  size_t dbbase = ((size_t)(b * 64 + (d >> 4))) * SEQ;
#pragma unroll
  for (int i = 0; i < 16; i++) {
    int l = l0 + rg + i * 4;
    float zr = b2f(xz[((size_t)b * SEQ + l) * E2 + DI + d]);
    float z = zr / (1.f + __expf(-zr));
    zgB[(dbbase + l) * 16 + (col & 15)] = f2b(z * wef);
  }
}

// ---------------- K5: x_dbl GEMM (reads blocked uB): xd[ch][t][64] ------------
__global__ __launch_bounds__(256) void k_xdbl(const ushort_t* __restrict__ uB,
    const ushort_t* __restrict__ xpwA, ushort_t* __restrict__ xdA) {
  __shared__ ushort_t As[64*32];
  __shared__ ushort_t Bs[64*32];
  int ch = blockIdx.y, br = ch >> 1;
  const ushort_t* xpw = xpwA + (size_t)br * KXP * DI;
  ushort_t* xd = xdA + (size_t)ch * SEQ * KXP;
  int t0 = blockIdx.x * 64;
  int tid = threadIdx.x, w = tid >> 6, lane = tid & 63;
  int lrow = lane & 15, lko = (lane >> 4) * 8;
  int row = tid >> 2, seg = tid & 3;
  f32x4 acc[4];
#pragma unroll
  for (int j = 0; j < 4; j++) acc[j] = (f32x4){0.f,0.f,0.f,0.f};
  for (int k0 = 0; k0 < DI; k0 += 32) {
    __syncthreads();
    glds16(uB + (((size_t)(ch*64 + (k0>>4) + (seg>>1)) * SEQ + t0 + row) * 16 + (seg&1)*8),
           &As[row*32 + seg*8]);
    glds16(xpw + (size_t)row * DI + k0 + seg * 8, &Bs[row*32 + seg*8]);
    __syncthreads();
    bf16x8 aF = *(const bf16x8*)&As[(w*16 + lrow)*32 + lko];
#pragma unroll
    for (int j = 0; j < 4; j++) {
      bf16x8 bF = *(const bf16x8*)&Bs[(j*16 + lrow)*32 + lko];
      acc[j] = __builtin_amdgcn_mfma_f32_16x16x32_bf16(aF, bF, acc[j], 0, 0, 0);
    }
  }
#pragma unroll
  for (int j = 0; j < 4; j++)
#pragma unroll
    for (int r = 0; r < 4; r++) {
      int t = t0 + w*16 + (lane>>4)*4 + r;
      xd[(size_t)t * KXP + j*16 + lrow] = f2b(acc[j][r]);
    }
}

// ---------------- K5b: expand xd B/C -> Bf/Cf[ch][n][t] f32 -------------------
__global__ __launch_bounds__(256) void k_bc(const ushort_t* __restrict__ xdA,
    float* __restrict__ Bf, float* __restrict__ Cf) {
  __shared__ float tb[128][34];
  int ch = blockIdx.y, t0 = blockIdx.x * 128;
  int tid = threadIdx.x;
  const ushort_t* xdb = xdA + (size_t)ch * SEQ * KXP;
#pragma unroll
  for (int i = 0; i < 2; i++) {
    int r = (tid >> 2) + i * 64;
    int q = tid & 3;
    const ushort_t* p = xdb + (size_t)(t0 + r) * KXP + 32 + q * 8;
    uint4 v = *(const uint4*)p;
    unsigned int wd[4] = {v.x, v.y, v.z, v.w};
    float* dst = &tb[r][q * 8];
#pragma unroll
    for (int j = 0; j < 4; j++) {
      dst[2*j]   = __uint_as_float(wd[j] << 16);
      dst[2*j+1] = __uint_as_float(wd[j] & 0xFFFF0000u);
    }
  }
  __syncthreads();
  int nn = tid >> 4, sg = tid & 15;
  float ob[8], oc[8];
#pragma unroll
  for (int j = 0; j < 8; j++) {
    ob[j] = tb[sg*8 + j][nn];
    oc[j] = tb[sg*8 + j][16 + nn];
  }
  float* Bp = Bf + ((size_t)ch * NST + nn) * SEQ + t0 + sg * 8;
  float* Cp = Cf + ((size_t)ch * NST + nn) * SEQ + t0 + sg * 8;
  *(float4*)Bp       = make_float4(ob[0],ob[1],ob[2],ob[3]);
  *(float4*)(Bp + 4) = make_float4(ob[4],ob[5],ob[6],ob[7]);
  *(float4*)Cp       = make_float4(oc[0],oc[1],oc[2],oc[3]);
  *(float4*)(Cp + 4) = make_float4(oc[4],oc[5],oc[6],oc[7]);
}

// ---------------- K7a: segmented local scan (also stores dlt over uB) ---------
// grid 3072 = ch(bid>>9) x seg((bid>>6)&7) x dblk(bid&63)
__global__ __launch_bounds__(256, 4) void k_scan1(
    const ushort_t* __restrict__ xdA, ushort_t* uB,
    const ushort_t* __restrict__ zgB, const float* __restrict__ Bf,
    const float* __restrict__ Cf, const float* __restrict__ dtwf,
    const float* __restrict__ dtbf, const float* __restrict__ alf,
    const float* __restrict__ ddf, float* __restrict__ sc,
    float* __restrict__ Hloc, float* __restrict__ Stot) {
  __shared__ __align__(16) float BS[4][16][18];
  __shared__ __align__(16) float CS[4][16][18];
  __shared__ float2 ddS[4][4][17];
  int bid = blockIdx.x;
  int dblk = bid & 63, seg = (bid >> 6) & 7, ch = bid >> 9;
  int br = ch >> 1, b = ch & 1;
  int tid = threadIdx.x, w = tid >> 6, lane = tid & 63, g = lane >> 4, n = lane & 15;
  int dloc = w * 4 + g;
  int d = dblk * 16 + dloc;
  float dtb_d = dtbf[br * DI + d];
  float Ap  = -__expf(alf[br * (DI*NST) + d * NST + n]);
  float Dd  = ddf[br * DI + d];
  const float* dwrow = dtwf + ((size_t)br * DI + d) * DTR;
  const ushort_t* xdb = xdA + (size_t)ch * SEQ * KXP;
  ushort_t* uBp = uB + ((size_t)(ch * 64 + dblk) * SEQ) * 16;   // read u, write dlt
  const ushort_t* zgp = zgB + ((size_t)(b  * 64 + dblk) * SEQ) * 16;
  const float* Bfp = Bf + ((size_t)ch * NST) * SEQ;
  const float* Cfp = Cf + ((size_t)ch * NST) * SEQ;
  float* srow = sc + (size_t)b * SEQ;
  float hst = 0.f, Sacc = 0.f;
  int sn = lane >> 2, sq = lane & 3;
  for (int t0 = seg * SEGL; t0 < seg * SEGL + SEGL; t0 += 16) {
    *(float4*)&BS[w][sn][sq*4] = *(const float4*)&Bfp[(size_t)sn * SEQ + t0 + sq*4];
    *(float4*)&CS[w][sn][sq*4] = *(const float4*)&Cfp[(size_t)sn * SEQ + t0 + sq*4];
    const ushort_t* rp = xdb + (size_t)(t0 + n) * KXP;
    uint4 q0 = *(const uint4*)(rp),      q1 = *(const uint4*)(rp + 8);
    uint4 q2 = *(const uint4*)(rp + 16), q3 = *(const uint4*)(rp + 24);
    float acc = dtb_d;
    {
      unsigned int wds[16] = {q0.x,q0.y,q0.z,q0.w, q1.x,q1.y,q1.z,q1.w,
                              q2.x,q2.y,q2.z,q2.w, q3.x,q3.y,q3.z,q3.w};
#pragma unroll
      for (int jj = 0; jj < 8; jj++) {
        float4 wv = *(const float4*)&dwrow[jj * 4];
        acc = fmaf(__uint_as_float(wds[2*jj]   << 16),         wv.x, acc);
        acc = fmaf(__uint_as_float(wds[2*jj]   & 0xFFFF0000u), wv.y, acc);
        acc = fmaf(__uint_as_float(wds[2*jj+1] << 16),         wv.z, acc);
        acc = fmaf(__uint_as_float(wds[2*jj+1] & 0xFFFF0000u), wv.w, acc);
      }
    }
    float dlt = (acc > 20.f) ? acc : log1pf(__expf(acc));
    Sacc += dlt;
    float u    = b2f(uBp[(size_t)(t0 + n) * 16 + dloc]);
    uBp[(size_t)(t0 + n) * 16 + dloc] = f2b(dlt);   // same address: order preserved
    float gate = b2f(zgp[(size_t)pmap(br, t0 + n) * 16 + dloc]);
    float du  = dlt * u;
    float dug = Dd * u * gate;
    ddS[w][g][n] = make_float2(dlt, du);
    float Bk[16], Ck[16];
#pragma unroll
    for (int j = 0; j < 4; j++) {
      *(float4*)&Bk[j*4] = *(const float4*)&BS[w][n][j*4];
      *(float4*)&Ck[j*4] = *(const float4*)&CS[w][n][j*4];
    }
    float hC[16];
#pragma unroll
    for (int k = 0; k < 16; k++) {
      float2 v = ddS[w][g][k];
      hst = fmaf(__expf(v.x * Ap), hst, v.y * Bk[k]);
      hC[k] = hst * Ck[k];
    }
    float a8[8], a4[4], a2[2], y;
#pragma unroll
    for (int j = 0; j < 8; j++) {
      float keep = (n & 8) ? hC[j+8] : hC[j];
      float send = (n & 8) ? hC[j]   : hC[j+8];
      a8[j] = keep + __shfl_xor(send, 8, 64);
    }
#pragma unroll
    for (int j = 0; j < 4; j++) {
      float keep = (n & 4) ? a8[j+4] : a8[j];
      float send = (n & 4) ? a8[j]   : a8[j+4];
      a4[j] = keep + __shfl_xor(send, 4, 64);
    }
#pragma unroll
    for (int j = 0; j < 2; j++) {
      float keep = (n & 2) ? a4[j+2] : a4[j];
      float send = (n & 2) ? a4[j]   : a4[j+2];
      a2[j] = keep + __shfl_xor(send, 2, 64);
    }
    {
      float keep = (n & 1) ? a2[1] : a2[0];
      float send = (n & 1) ? a2[0] : a2[1];
      y = keep + __shfl_xor(send, 1, 64);
    }
    y = fmaf(y, gate, dug);
    y += __shfl_xor(y, 16, 64);
    y += __shfl_xor(y, 32, 64);
    if (lane < 16) atomicAdd(srow + omap(br, t0 + lane), y);
  }
  Hloc[(((size_t)ch * NSEG + seg) * 1024 + d) * 16 + n] = hst;
  Sacc += __shfl_xor(Sacc, 1, 64);
  Sacc += __shfl_xor(Sacc, 2, 64);
  Sacc += __shfl_xor(Sacc, 4, 64);
  Sacc += __shfl_xor(Sacc, 8, 64);
  if (n == 0) Stot[((size_t)ch * NSEG + seg) * 1024 + d] = Sacc;
}

// ---------------- K7b: stitch segment states ----------------------------------
__global__ __launch_bounds__(256) void k_stitch(const float* __restrict__ Stot,
    const float* __restrict__ Hloc, const float* __restrict__ alf,
    float* __restrict__ Hin) {
  int idx = blockIdx.x * 256 + threadIdx.x;     // 98304 = 6*1024*16
  int ch = idx >> 14, rem = idx & 16383, d = rem >> 4, n = rem & 15;
  int br = ch >> 1;
  float A = -__expf(alf[(size_t)br * (DI*NST) + d * NST + n]);
  float h = 0.f;
  for (int s = 0; s < NSEG; s++) {
    size_t base = ((size_t)ch * NSEG + s) * 1024 + d;
    Hin[base * 16 + n] = h;
    h = __expf(A * Stot[base]) * h + Hloc[base * 16 + n];
  }
}

// ---------------- K7c: carry correction (R9 shape, delta precomputed) ---------
// grid 1536 = ch(bid>>8) x cg(bid&255); all blocks co-resident at 6/CU.
__global__ __launch_bounds__(256, 6) void k_scan2(
    const ushort_t* __restrict__ zgB, const ushort_t* __restrict__ dltB,
    const float* __restrict__ Cf, const float* __restrict__ alf,
    const float* __restrict__ Hin, float* __restrict__ sc) {
  __shared__ float red[4][72];
  int ch = blockIdx.x >> 8, cg = blockIdx.x & 255;
  int br = ch >> 1, b = ch & 1;
  int tid = threadIdx.x, w = tid >> 6, lane = tid & 63;
  int d = cg * 4 + w;
  float A_[16];
#pragma unroll
  for (int nn = 0; nn < 16; nn++)
    A_[nn] = -__expf(alf[(size_t)br * (DI*NST) + d * NST + nn]);
  const ushort_t* dlp = dltB + ((size_t)(ch * 64 + (d >> 4)) * SEQ) * 16;
  const ushort_t* zgp = zgB  + ((size_t)(b  * 64 + (d >> 4)) * SEQ) * 16;
  const float* Cfp = Cf + (size_t)ch * NST * SEQ;
  int dsub = d & 15;
  float* srow = sc + (size_t)b * SEQ;
  for (int seg = 1; seg < NSEG; seg++) {
    float Hn[16];
    const float* hp = Hin + (((size_t)ch * NSEG + seg) * 1024 + d) * 16;
#pragma unroll
    for (int nn = 0; nn < 16; nn++) Hn[nn] = hp[nn];
    float carry = 0.f;
    for (int w0 = seg * SEGL; w0 < seg * SEGL + SEGL; w0 += 64) {
      int t = w0 + lane;
      float dlt = b2f(dlp[(size_t)t * 16 + dsub]);
      float S = dlt;
#pragma unroll
      for (int ofs = 1; ofs < 64; ofs <<= 1) {
        float v = __shfl_up(S, ofs, 64);
        if (lane >= ofs) S += v;
      }
      float tot = __shfl(S, 63, 64);
      S += carry; carry += tot;
      float corr = 0.f;
#pragma unroll
      for (int nn = 0; nn < 16; nn++) {
        float Cn = Cfp[(size_t)nn * SEQ + t];
        corr = fmaf(Cn * Hn[nn], __expf(A_[nn] * S), corr);
      }
      float gate = b2f(zgp[(size_t)pmap(br, t) * 16 + dsub]);
      float y = corr * gate;
      red[w][lane] = y;
      __syncthreads();
      if (w == 0) {
        float ytot = red[0][lane] + red[1][lane] + red[2][lane] + red[3][lane];
        atomicAdd(srow + omap(br, t), ytot);
      }
      __syncthreads();
    }
  }
}

// ---------------- K8: w_eff[d] = lin_w . out_proj_w[:,d]; zero score_acc ------
__global__ __launch_bounds__(256) void k_weff_init(const ushort_t* __restrict__ opwb,
    const ushort_t* __restrict__ lwb, float* __restrict__ weff, float* __restrict__ sc) {
  int i = blockIdx.x * 256 + threadIdx.x;
  if (i < DI) {
    float s = 0.f;
    for (int o = 0; o < DIMX; o++) s += b2f(lwb[o]) * b2f(opwb[(size_t)o * DI + i]);
    weff[i] = s;
  }
  int j = i - DI;
  if (j >= 0 && j < 2 * SEQ) sc[j] = 0.f;
}

// ---------------- K9: outputs (f32): group interp+sigmoid, individual ---------
__global__ __launch_bounds__(256) void k_out(const float* __restrict__ g0,
    const float* __restrict__ g1, const float* __restrict__ g2,
    const float* __restrict__ sc, const float* __restrict__ lbf,
    float* __restrict__ out) {
  int idx = blockIdx.x * 256 + threadIdx.x;
  if (idx < 3 * SEQ) {
    int j = idx / SEQ, t = idx % SEQ;
    const float* g = (j == 0) ? g0 : (j == 1) ? g1 : g2;
    float pos = t * ((float)(LGS - 1) / (float)(SEQ - 1));
    int i0 = (int)floorf(pos);
    if (i0 < 0) i0 = 0; if (i0 > LGS - 2) i0 = LGS - 2;
    float wt = pos - (float)i0;
    float v = g[i0] * (1.f - wt) + g[i0 + 1] * wt;
    out[idx] = 1.f / (1.f + __expf(-v));
  } else if (idx < 5 * SEQ) {
    float t = sc[idx - 3 * SEQ] + lbf[0];
    out[idx] = 1.f / (1.f + __expf(-t));
  }
}

extern "C" void kernel_launch(void* const* d_in, const int* in_sizes, int n_in,
                              void* d_out, int out_size, void* d_ws, size_t ws_size,
                              hipStream_t stream) {
  char* ws = (char*)d_ws;
  ushort_t* lwb   = (ushort_t*)(ws + OFF_LWB);
  float*    lngf  = (float*)(ws + OFF_LNGF);
  float*    lnbf  = (float*)(ws + OFF_LNBF);
  float*    lbf   = (float*)(ws + OFF_LBF);
  float*    cwf   = (float*)(ws + OFF_CWF);
  float*    cbf   = (float*)(ws + OFF_CBF);
  float*    dtbf  = (float*)(ws + OFF_DTBF);
  float*    alf   = (float*)(ws + OFF_ALF);
  float*    ddf   = (float*)(ws + OFF_DDF);
  float*    weff  = (float*)(ws + OFF_WEFF);
  float*    sc    = (float*)(ws + OFF_SC);
  ushort_t* dtwb  = (ushort_t*)(ws + OFF_DTWB);
  float*    dtwf  = (float*)(ws + OFF_DTWF);
  ushort_t* xpwb  = (ushort_t*)(ws + OFF_XPWB);
  ushort_t* opwb  = (ushort_t*)(ws + OFF_OPWB);
  ushort_t* inwb  = (ushort_t*)(ws + OFF_INWB);
  ushort_t* xd    = (ushort_t*)(ws + OFF_XD);
  ushort_t* xz    = (ushort_t*)(ws + OFF_XZ);
  float*    Bf    = (float*)(ws + OFF_BF);
  float*    Cf    = (float*)(ws + OFF_CF);
  ushort_t* uB    = (ushort_t*)(ws + OFF_UB);
  ushort_t* h     = (ushort_t*)(ws + OFF_H);
  ushort_t* zgB   = (ushort_t*)(ws + OFF_ZGB);
  float*    Hloc  = (float*)(ws + OFF_HLOC);
  float*    Hin   = (float*)(ws + OFF_HIN);
  float*    Stot  = (float*)(ws + OFF_STOT);
  float*    OUT   = (float*)d_out;

  Tab tab;
  int c = 0;
  tab.e[c++] = {d_in[3], inwb, E2 * DIMX, 0};
  tab.e[c++] = {d_in[4], opwb, DIMX * DI, 0};
  tab.e[c++] = {d_in[5], lwb, DIMX, 0};
  for (int br = 0; br < 3; br++) {
    int base = 10 + br * 7;
    tab.e[c++] = {d_in[base + 2], xpwb + (size_t)br * KXP * DI, KXP * DI, 0};
    tab.e[c++] = {d_in[base + 3], dtwf + (size_t)br * DI * DTR, DI * DTR, 1};
  }
  tab.e[c++] = {d_in[1], lngf, DIMX, 1};
  tab.e[c++] = {d_in[2], lnbf, DIMX, 1};
  tab.e[c++] = {d_in[6], lbf, 1, 1};
  for (int br = 0; br < 3; br++) {
    int base = 10 + br * 7;
    tab.e[c++] = {d_in[base + 0], cwf + (size_t)br * DI * 4, DI * 4, 1};
    tab.e[c++] = {d_in[base + 1], cbf + (size_t)br * DI, DI, 1};
    tab.e[c++] = {d_in[base + 4], dtbf + (size_t)br * DI, DI, 1};
    tab.e[c++] = {d_in[base + 5], alf + (size_t)br * DI * NST, DI * NST, 1};
    tab.e[c++] = {d_in[base + 6], ddf + (size_t)br * DI, DI, 1};
  }

  dim3 blk(256);
  k_import<<<dim3(64, c), blk, 0, stream>>>(tab, c);
  k_weff_init<<<44, blk, 0, stream>>>(opwb, lwb, weff, sc);
  k_ln<<<2560, blk, 0, stream>>>((const float*)d_in[0], lngf, lnbf, h);
  k_inproj<<<dim3(80, 16), blk, 0, stream>>>(h, inwb, xz);
  k_conv<<<dim3(80, 16, 6), blk, 0, stream>>>(xz, cwf, cbf, uB);
  k_zg<<<dim3(80, 16, 2), blk, 0, stream>>>(xz, weff, zgB);
  k_xdbl<<<dim3(80, 6), blk, 0, stream>>>(uB, xpwb, xd);
  k_bc<<<dim3(40, 6), blk, 0, stream>>>(xd, Bf, Cf);
  k_scan1<<<3072, blk, 0, stream>>>(xd, uB, zgB, Bf, Cf, dtwf, dtbf, alf, ddf,
                                    sc, Hloc, Stot);
  k_stitch<<<384, blk, 0, stream>>>(Stot, Hloc, alf, Hin);
  k_scan2<<<1536, blk, 0, stream>>>(zgB, uB, Cf, alf, Hin, sc);
  k_out<<<100, blk, 0, stream>>>((const float*)d_in[7], (const float*)d_in[8],
                                 (const float*)d_in[9], sc, lbf, OUT);
}

// Round 12
// 824.530 us; speedup vs baseline: 1.8981x; 1.0321x over previous
//
#include <hip/hip_runtime.h>
#include <stdint.h>

#define SEQ  5120
#define DIMX 512
#define E2   2048
#define DI   1024
#define NST  16
#define DTR  32
#define KXP  64
#define LGS  2048
#define NSL  5
#define NSEG 8
#define SEGL 640

typedef unsigned short ushort_t;
typedef __attribute__((ext_vector_type(8))) __bf16 bf16x8;
typedef __attribute__((ext_vector_type(4))) float f32x4;

__device__ __forceinline__ float b2f(ushort_t u) {
  union { unsigned int i; float f; } v; v.i = ((unsigned int)u) << 16; return v.f;
}
__device__ __forceinline__ ushort_t f2b(float f) {
  union { float f; unsigned int i; } v; v.f = f;
  unsigned int u = v.i;
  return (ushort_t)((u + 0x7FFFu + ((u >> 16) & 1u)) >> 16);
}

#define AS1 __attribute__((address_space(1)))
#define AS3 __attribute__((address_space(3)))
__device__ __forceinline__ void glds16(const void* g, void* l) {
  __builtin_amdgcn_global_load_lds((const AS1 void*)g, (AS3 void*)l, 16, 0, 0);
}

__device__ __forceinline__ int pmap(int br, int t) {   // scan pos -> data pos
  return (br == 0) ? t : (br == 1) ? (SEQ - 1 - t) : ((t % NSL) * 1024 + t / NSL);
}
__device__ __forceinline__ int omap(int br, int t) {   // scan pos -> output pos
  return (br == 0) ? t : (br == 1) ? (SEQ - 1 - t) : ((t & 1023) * NSL + (t >> 10));
}

// ---------------- workspace layout (bytes) ------------------------------------
#define OFF_LWB   ((size_t)256)
#define OFF_LNGF  ((size_t)1280)
#define OFF_LNBF  ((size_t)3328)
#define OFF_LBF   ((size_t)5376)
#define OFF_CWF   ((size_t)5632)
#define OFF_CBF   ((size_t)54784)
#define OFF_DTBF  ((size_t)67072)
#define OFF_ALF   ((size_t)79360)
#define OFF_DDF   ((size_t)275968)
#define OFF_WEFF  ((size_t)288256)
#define OFF_SC    ((size_t)292352)
#define OFF_DTWB  ((size_t)333312)      // bf16 dt_w, 3*1024*32*2 = 196,608
#define OFF_XPWB  ((size_t)529920)
#define OFF_OPWB  ((size_t)923136)
#define OFF_INWB  ((size_t)1971712)     // ends 4,068,864
#define OFF_XD    ((size_t)4068864)     // 6*5120*64*2 = 3,932,160 -> 8,001,024
#define OFF_DLTB  ((size_t)8001024)     // 6*5120*1024*2 = 62,914,560 -> 70,915,584
#define OFF_XZ    OFF_DLTB              // xz (42 MB) nested; dead before k_delta writes
#define OFF_BF    ((size_t)70915584)    // 1,966,080 -> 72,881,664
#define OFF_CF    ((size_t)72881664)    // 1,966,080 -> 74,847,744
#define OFF_HLOC  ((size_t)74847744)    // 3,145,728 -> 77,993,472
#define OFF_HIN   ((size_t)77993472)    // 3,145,728 -> 81,139,200
#define OFF_STOT  ((size_t)81139200)    // 196,608  -> 81,335,808
#define OFF_UB    ((size_t)81335808)    // 62,914,560 -> 144,250,368
#define OFF_H     OFF_UB                // ln-out h (10 MB) nested; dead before conv
#define OFF_ZGB   ((size_t)144250368)   // 20,971,520 -> 165,221,888
// total ~165.2 MiB

// ---------------- K0: batched import (f32 params -> ws, bf16 or f32) ----------
struct Ent { const void* s; void* d; int n; int fmt; };
struct Tab { Ent e[32]; };

__global__ __launch_bounds__(256) void k_import(Tab t, int cnt) {
  int id = blockIdx.y;
  if (id >= cnt) return;
  Ent E = t.e[id];
  int stride = gridDim.x * 256;
  const float* s = (const float*)E.s;
  if (E.fmt == 0) {
    ushort_t* dst = (ushort_t*)E.d;
    for (int i = blockIdx.x * 256 + threadIdx.x; i < E.n; i += stride) dst[i] = f2b(s[i]);
  } else {
    float* dst = (float*)E.d;
    for (int i = blockIdx.x * 256 + threadIdx.x; i < E.n; i += stride) dst[i] = s[i];
  }
}

// ---------------- K1: LayerNorm + ReLU -> h (bf16, both batches) --------------
__global__ __launch_bounds__(256) void k_ln(const float* __restrict__ x,
    const float* __restrict__ gam, const float* __restrict__ bet,
    ushort_t* __restrict__ h) {
  int token = blockIdx.x * 4 + (threadIdx.x >> 6);
  int lane = threadIdx.x & 63;
  const float* row = x + (size_t)token * DIMX + lane * 8;
  float4 a0 = *(const float4*)(row);
  float4 a1 = *(const float4*)(row + 4);
  float v[8] = {a0.x,a0.y,a0.z,a0.w,a1.x,a1.y,a1.z,a1.w};
  float s = 0.f, ss = 0.f;
#pragma unroll
  for (int i = 0; i < 8; i++) { s += v[i]; ss += v[i]*v[i]; }
#pragma unroll
  for (int m = 1; m < 64; m <<= 1) { s += __shfl_xor(s, m, 64); ss += __shfl_xor(ss, m, 64); }
  float mean = s * (1.f / DIMX);
  float rs = rsqrtf(ss * (1.f / DIMX) - mean * mean + 1e-5f);
  ushort_t o[8];
#pragma unroll
  for (int i = 0; i < 8; i++) {
    float y = (v[i] - mean) * rs * gam[lane*8+i] + bet[lane*8+i];
    o[i] = f2b(fmaxf(y, 0.f));
  }
  ushort_t* orow = h + (size_t)token * DIMX + lane * 8;
  *(ushort4*)(orow)     = make_ushort4(o[0],o[1],o[2],o[3]);
  *(ushort4*)(orow + 4) = make_ushort4(o[4],o[5],o[6],o[7]);
}

// ---------------- K2: in_proj GEMM (M=10240): xz[bl][e] = h @ W^T -------------
__global__ __launch_bounds__(256) void k_inproj(const ushort_t* __restrict__ hA,
    const ushort_t* __restrict__ Wb, ushort_t* __restrict__ xz) {
  __shared__ ushort_t As[128*32];
  __shared__ ushort_t Bs[128*32];
  const int tid = threadIdx.x;
  const int w = tid >> 6, lane = tid & 63;
  const int wr = w >> 1, wc = w & 1;
  const int m0 = blockIdx.x * 128, n0 = blockIdx.y * 128;
  const int lrow = lane & 15, lko = (lane >> 4) * 8;
  f32x4 acc[4][4];
#pragma unroll
  for (int i = 0; i < 4; i++)
#pragma unroll
    for (int j = 0; j < 4; j++) acc[i][j] = (f32x4){0.f,0.f,0.f,0.f};
  for (int k0 = 0; k0 < DIMX; k0 += 32) {
    __syncthreads();
#pragma unroll
    for (int r = 0; r < 2; r++) {
      int e = r * 256 + tid;
      int row = e >> 2, seg = e & 3;
      glds16(hA + (size_t)(m0 + row) * DIMX + k0 + seg * 8, &As[row*32 + seg*8]);
      glds16(Wb + (size_t)(n0 + row) * DIMX + k0 + seg * 8, &Bs[row*32 + seg*8]);
    }
    __syncthreads();
    bf16x8 aF[4], bF[4];
#pragma unroll
    for (int i = 0; i < 4; i++)
      aF[i] = *(const bf16x8*)&As[(wr*64 + i*16 + lrow)*32 + lko];
#pragma unroll
    for (int j = 0; j < 4; j++)
      bF[j] = *(const bf16x8*)&Bs[(wc*64 + j*16 + lrow)*32 + lko];
#pragma unroll
    for (int i = 0; i < 4; i++)
#pragma unroll
      for (int j = 0; j < 4; j++)
        acc[i][j] = __builtin_amdgcn_mfma_f32_16x16x32_bf16(aF[i], bF[j], acc[i][j], 0, 0, 0);
  }
#pragma unroll
  for (int i = 0; i < 4; i++)
#pragma unroll
    for (int j = 0; j < 4; j++)
#pragma unroll
      for (int r = 0; r < 4; r++) {
        int m = m0 + wr*64 + i*16 + (lane>>4)*4 + r;
        int n = n0 + wc*64 + j*16 + lrow;
        xz[(size_t)m * E2 + n] = f2b(acc[i][j][r]);
      }
}

// ---------------- K4: conv + silu -> uB[ch][d>>4][t][16] (blocked) ------------
__global__ __launch_bounds__(256) void k_conv(const ushort_t* __restrict__ xz,
    const float* __restrict__ cwA, const float* __restrict__ cbA,
    ushort_t* __restrict__ uB) {
  __shared__ ushort_t xs[67][64];
  int ch = blockIdx.z, br = ch >> 1, b = ch & 1;
  int t0 = blockIdx.x * 64, d0 = blockIdx.y * 64;
  int tid = threadIdx.x, col = tid & 63, rg = tid >> 6;
  const float* cw = cwA + (size_t)br * DI * 4;
  const float* cb = cbA + (size_t)br * DI;
#pragma unroll
  for (int i = 0; i < 17; i++) {
    int row = rg + i * 4;
    if (row < 67) {
      int tau = t0 - 3 + row;
      ushort_t val = 0;
      if (tau >= 0) val = xz[((size_t)b * SEQ + pmap(br, tau)) * E2 + d0 + col];
      xs[row][col] = val;
    }
  }
  __syncthreads();
  int d = d0 + col;
  float w0 = cw[d*4+0], w1 = cw[d*4+1], w2 = cw[d*4+2], w3 = cw[d*4+3];
  float bias = cb[d];
  size_t dbbase = ((size_t)(ch * 64 + (d >> 4))) * SEQ;
#pragma unroll
  for (int i = 0; i < 16; i++) {
    int ti = rg + i * 4;
    float a = bias + w0*b2f(xs[ti][col]) + w1*b2f(xs[ti+1][col])
                   + w2*b2f(xs[ti+2][col]) + w3*b2f(xs[ti+3][col]);
    float val = a / (1.f + __expf(-a));
    uB[(dbbase + t0 + ti) * 16 + (col & 15)] = f2b(val);
  }
}

// ---------------- K4b: gate precompute -> zgB[b][d>>4][l][16] (blocked) -------
__global__ __launch_bounds__(256) void k_zg(const ushort_t* __restrict__ xz,
    const float* __restrict__ weff, ushort_t* __restrict__ zgB) {
  int b = blockIdx.z;
  int l0 = blockIdx.x * 64, d0 = blockIdx.y * 64;
  int tid = threadIdx.x, col = tid & 63, rg = tid >> 6;
  int d = d0 + col;
  float wef = weff[d];
  size_t dbbase = ((size_t)(b * 64 + (d >> 4))) * SEQ;
#pragma unroll
  for (int i = 0; i < 16; i++) {
    int l = l0 + rg + i * 4;
    float zr = b2f(xz[((size_t)b * SEQ + l) * E2 + DI + d]);
    float z = zr / (1.f + __expf(-zr));
    zgB[(dbbase + l) * 16 + (col & 15)] = f2b(z * wef);
  }
}

// ---------------- K5: x_dbl GEMM (reads blocked uB): xd[ch][t][64] ------------
__global__ __launch_bounds__(256) void k_xdbl(const ushort_t* __restrict__ uB,
    const ushort_t* __restrict__ xpwA, ushort_t* __restrict__ xdA) {
  __shared__ ushort_t As[64*32];
  __shared__ ushort_t Bs[64*32];
  int ch = blockIdx.y, br = ch >> 1;
  const ushort_t* xpw = xpwA + (size_t)br * KXP * DI;
  ushort_t* xd = xdA + (size_t)ch * SEQ * KXP;
  int t0 = blockIdx.x * 64;
  int tid = threadIdx.x, w = tid >> 6, lane = tid & 63;
  int lrow = lane & 15, lko = (lane >> 4) * 8;
  int row = tid >> 2, seg = tid & 3;
  f32x4 acc[4];
#pragma unroll
  for (int j = 0; j < 4; j++) acc[j] = (f32x4){0.f,0.f,0.f,0.f};
  for (int k0 = 0; k0 < DI; k0 += 32) {
    __syncthreads();
    glds16(uB + (((size_t)(ch*64 + (k0>>4) + (seg>>1)) * SEQ + t0 + row) * 16 + (seg&1)*8),
           &As[row*32 + seg*8]);
    glds16(xpw + (size_t)row * DI + k0 + seg * 8, &Bs[row*32 + seg*8]);
    __syncthreads();
    bf16x8 aF = *(const bf16x8*)&As[(w*16 + lrow)*32 + lko];
#pragma unroll
    for (int j = 0; j < 4; j++) {
      bf16x8 bF = *(const bf16x8*)&Bs[(j*16 + lrow)*32 + lko];
      acc[j] = __builtin_amdgcn_mfma_f32_16x16x32_bf16(aF, bF, acc[j], 0, 0, 0);
    }
  }
#pragma unroll
  for (int j = 0; j < 4; j++)
#pragma unroll
    for (int r = 0; r < 4; r++) {
      int t = t0 + w*16 + (lane>>4)*4 + r;
      xd[(size_t)t * KXP + j*16 + lrow] = f2b(acc[j][r]);
    }
}

// ---------------- K5b: expand xd B/C -> Bf/Cf[ch][n][t] f32 -------------------
__global__ __launch_bounds__(256) void k_bc(const ushort_t* __restrict__ xdA,
    float* __restrict__ Bf, float* __restrict__ Cf) {
  __shared__ float tb[128][34];
  int ch = blockIdx.y, t0 = blockIdx.x * 128;
  int tid = threadIdx.x;
  const ushort_t* xdb = xdA + (size_t)ch * SEQ * KXP;
#pragma unroll
  for (int i = 0; i < 2; i++) {
    int r = (tid >> 2) + i * 64;
    int q = tid & 3;
    const ushort_t* p = xdb + (size_t)(t0 + r) * KXP + 32 + q * 8;
    uint4 v = *(const uint4*)p;
    unsigned int wd[4] = {v.x, v.y, v.z, v.w};
    float* dst = &tb[r][q * 8];
#pragma unroll
    for (int j = 0; j < 4; j++) {
      dst[2*j]   = __uint_as_float(wd[j] << 16);
      dst[2*j+1] = __uint_as_float(wd[j] & 0xFFFF0000u);
    }
  }
  __syncthreads();
  int nn = tid >> 4, sg = tid & 15;
  float ob[8], oc[8];
#pragma unroll
  for (int j = 0; j < 8; j++) {
    ob[j] = tb[sg*8 + j][nn];
    oc[j] = tb[sg*8 + j][16 + nn];
  }
  float* Bp = Bf + ((size_t)ch * NST + nn) * SEQ + t0 + sg * 8;
  float* Cp = Cf + ((size_t)ch * NST + nn) * SEQ + t0 + sg * 8;
  *(float4*)Bp       = make_float4(ob[0],ob[1],ob[2],ob[3]);
  *(float4*)(Bp + 4) = make_float4(ob[4],ob[5],ob[6],ob[7]);
  *(float4*)Cp       = make_float4(oc[0],oc[1],oc[2],oc[3]);
  *(float4*)(Cp + 4) = make_float4(oc[4],oc[5],oc[6],oc[7]);
}

// ---------------- K6: delta GEMM (K=32) + softplus -> dltB (blocked) ----------
// grid (40 t-tiles, 8 d-tiles, 6 ch)
__global__ __launch_bounds__(256) void k_delta(const ushort_t* __restrict__ xdA,
    const ushort_t* __restrict__ dtwb, const float* __restrict__ dtbf,
    ushort_t* __restrict__ dltB) {
  __shared__ ushort_t As[128*32];
  __shared__ ushort_t Bs[128*32];
  int ch = blockIdx.z, br = ch >> 1;
  int t0 = blockIdx.x * 128, d0 = blockIdx.y * 128;
  int tid = threadIdx.x, w = tid >> 6, lane = tid & 63;
  int wr = w >> 1, wc = w & 1;
  int lrow = lane & 15, lko = (lane >> 4) * 8;
  const ushort_t* xdb = xdA + (size_t)ch * SEQ * KXP;
  const ushort_t* dwp = dtwb + (size_t)br * DI * DTR;
#pragma unroll
  for (int r = 0; r < 2; r++) {
    int e = r * 256 + tid;
    int row = e >> 2, seg = e & 3;
    glds16(xdb + (size_t)(t0 + row) * KXP + seg * 8, &As[row*32 + seg*8]);
    glds16(dwp + (size_t)(d0 + row) * DTR + seg * 8, &Bs[row*32 + seg*8]);
  }
  __syncthreads();
  bf16x8 aF[4], bF[4];
#pragma unroll
  for (int i = 0; i < 4; i++)
    aF[i] = *(const bf16x8*)&As[(wr*64 + i*16 + lrow)*32 + lko];
#pragma unroll
  for (int j = 0; j < 4; j++)
    bF[j] = *(const bf16x8*)&Bs[(wc*64 + j*16 + lrow)*32 + lko];
  f32x4 acc[4][4];
#pragma unroll
  for (int i = 0; i < 4; i++)
#pragma unroll
    for (int j = 0; j < 4; j++) {
      acc[i][j] = (f32x4){0.f,0.f,0.f,0.f};
      acc[i][j] = __builtin_amdgcn_mfma_f32_16x16x32_bf16(aF[i], bF[j], acc[i][j], 0, 0, 0);
    }
#pragma unroll
  for (int i = 0; i < 4; i++)
#pragma unroll
    for (int j = 0; j < 4; j++)
#pragma unroll
      for (int r = 0; r < 4; r++) {
        int t = t0 + wr*64 + i*16 + (lane>>4)*4 + r;
        int d = d0 + wc*64 + j*16 + lrow;
        float xv = acc[i][j][r] + dtbf[br * DI + d];
        float sp = (xv > 20.f) ? xv : log1pf(__expf(xv));
        dltB[(((size_t)(ch*64 + (d>>4))) * SEQ + t) * 16 + (d & 15)] = f2b(sp);
      }
}

// ---------------- K7a: segmented local scan (delta precomputed) ---------------
// grid 3072 = ch(bid>>9) x seg((bid>>6)&7) x dblk(bid&63)
__global__ __launch_bounds__(256, 4) void k_scan1(
    const ushort_t* __restrict__ dltB, const ushort_t* __restrict__ uB,
    const ushort_t* __restrict__ zgB, const float* __restrict__ Bf,
    const float* __restrict__ Cf, const float* __restrict__ alf,
    const float* __restrict__ ddf, float* __restrict__ sc,
    float* __restrict__ Hloc, float* __restrict__ Stot) {
  __shared__ __align__(16) float BS[4][16][18];
  __shared__ __align__(16) float CS[4][16][18];
  __shared__ float2 ddS[4][4][17];
  int bid = blockIdx.x;
  int dblk = bid & 63, seg = (bid >> 6) & 7, ch = bid >> 9;
  int br = ch >> 1, b = ch & 1;
  int tid = threadIdx.x, w = tid >> 6, lane = tid & 63, g = lane >> 4, n = lane & 15;
  int dloc = w * 4 + g;
  int d = dblk * 16 + dloc;
  float Ap = -__expf(alf[br * (DI*NST) + d * NST + n]);
  float Dd = ddf[br * DI + d];
  const ushort_t* dlp = dltB + ((size_t)(ch * 64 + dblk) * SEQ) * 16;
  const ushort_t* uBp = uB   + ((size_t)(ch * 64 + dblk) * SEQ) * 16;
  const ushort_t* zgp = zgB  + ((size_t)(b  * 64 + dblk) * SEQ) * 16;
  const float* Bfp = Bf + ((size_t)ch * NST) * SEQ;
  const float* Cfp = Cf + ((size_t)ch * NST) * SEQ;
  float* srow = sc + (size_t)b * SEQ;
  float hst = 0.f, Sacc = 0.f;
  int sn = lane >> 2, sq = lane & 3;
  for (int t0 = seg * SEGL; t0 < seg * SEGL + SEGL; t0 += 16) {
    *(float4*)&BS[w][sn][sq*4] = *(const float4*)&Bfp[(size_t)sn * SEQ + t0 + sq*4];
    *(float4*)&CS[w][sn][sq*4] = *(const float4*)&Cfp[(size_t)sn * SEQ + t0 + sq*4];
    float dlt  = b2f(dlp[(size_t)(t0 + n) * 16 + dloc]);
    Sacc += dlt;
    float u    = b2f(uBp[(size_t)(t0 + n) * 16 + dloc]);
    float gate = b2f(zgp[(size_t)pmap(br, t0 + n) * 16 + dloc]);
    float du  = dlt * u;
    float dug = Dd * u * gate;
    ddS[w][g][n] = make_float2(dlt, du);
    float Bk[16], Ck[16];
#pragma unroll
    for (int j = 0; j < 4; j++) {
      *(float4*)&Bk[j*4] = *(const float4*)&BS[w][n][j*4];
      *(float4*)&Ck[j*4] = *(const float4*)&CS[w][n][j*4];
    }
    float hC[16];
#pragma unroll
    for (int k = 0; k < 16; k++) {
      float2 v = ddS[w][g][k];
      hst = fmaf(__expf(v.x * Ap), hst, v.y * Bk[k]);
      hC[k] = hst * Ck[k];
    }
    float a8[8], a4[4], a2[2], y;
#pragma unroll
    for (int j = 0; j < 8; j++) {
      float keep = (n & 8) ? hC[j+8] : hC[j];
      float send = (n & 8) ? hC[j]   : hC[j+8];
      a8[j] = keep + __shfl_xor(send, 8, 64);
    }
#pragma unroll
    for (int j = 0; j < 4; j++) {
      float keep = (n & 4) ? a8[j+4] : a8[j];
      float send = (n & 4) ? a8[j]   : a8[j+4];
      a4[j] = keep + __shfl_xor(send, 4, 64);
    }
#pragma unroll
    for (int j = 0; j < 2; j++) {
      float keep = (n & 2) ? a4[j+2] : a4[j];
      float send = (n & 2) ? a4[j]   : a4[j+2];
      a2[j] = keep + __shfl_xor(send, 2, 64);
    }
    {
      float keep = (n & 1) ? a2[1] : a2[0];
      float send = (n & 1) ? a2[0] : a2[1];
      y = keep + __shfl_xor(send, 1, 64);
    }
    y = fmaf(y, gate, dug);
    y += __shfl_xor(y, 16, 64);
    y += __shfl_xor(y, 32, 64);
    if (lane < 16) atomicAdd(srow + omap(br, t0 + lane), y);
  }
  Hloc[(((size_t)ch * NSEG + seg) * 1024 + d) * 16 + n] = hst;
  Sacc += __shfl_xor(Sacc, 1, 64);
  Sacc += __shfl_xor(Sacc, 2, 64);
  Sacc += __shfl_xor(Sacc, 4, 64);
  Sacc += __shfl_xor(Sacc, 8, 64);
  if (n == 0) Stot[((size_t)ch * NSEG + seg) * 1024 + d] = Sacc;
}

// ---------------- K7b: stitch segment states ----------------------------------
__global__ __launch_bounds__(256) void k_stitch(const float* __restrict__ Stot,
    const float* __restrict__ Hloc, const float* __restrict__ alf,
    float* __restrict__ Hin) {
  int idx = blockIdx.x * 256 + threadIdx.x;     // 98304 = 6*1024*16
  int ch = idx >> 14, rem = idx & 16383, d = rem >> 4, n = rem & 15;
  int br = ch >> 1;
  float A = -__expf(alf[(size_t)br * (DI*NST) + d * NST + n]);
  float h = 0.f;
  for (int s = 0; s < NSEG; s++) {
    size_t base = ((size_t)ch * NSEG + s) * 1024 + d;
    Hin[base * 16 + n] = h;
    h = __expf(A * Stot[base]) * h + Hloc[base * 16 + n];
  }
}

// ---------------- K7c: carry correction (R9 shape, delta precomputed) ---------
// grid 1536 = ch(bid>>8) x cg(bid&255); all blocks co-resident at 6/CU.
__global__ __launch_bounds__(256, 6) void k_scan2(
    const ushort_t* __restrict__ zgB, const ushort_t* __restrict__ dltB,
    const float* __restrict__ Cf, const float* __restrict__ alf,
    const float* __restrict__ Hin, float* __restrict__ sc) {
  __shared__ float red[4][72];
  int ch = blockIdx.x >> 8, cg = blockIdx.x & 255;
  int br = ch >> 1, b = ch & 1;
  int tid = threadIdx.x, w = tid >> 6, lane = tid & 63;
  int d = cg * 4 + w;
  float A_[16];
#pragma unroll
  for (int nn = 0; nn < 16; nn++)
    A_[nn] = -__expf(alf[(size_t)br * (DI*NST) + d * NST + nn]);
  const ushort_t* dlp = dltB + ((size_t)(ch * 64 + (d >> 4)) * SEQ) * 16;
  const ushort_t* zgp = zgB  + ((size_t)(b  * 64 + (d >> 4)) * SEQ) * 16;
  const float* Cfp = Cf + (size_t)ch * NST * SEQ;
  int dsub = d & 15;
  float* srow = sc + (size_t)b * SEQ;
  for (int seg = 1; seg < NSEG; seg++) {
    float Hn[16];
    const float* hp = Hin + (((size_t)ch * NSEG + seg) * 1024 + d) * 16;
#pragma unroll
    for (int nn = 0; nn < 16; nn++) Hn[nn] = hp[nn];
    float carry = 0.f;
    for (int w0 = seg * SEGL; w0 < seg * SEGL + SEGL; w0 += 64) {
      int t = w0 + lane;
      float dlt = b2f(dlp[(size_t)t * 16 + dsub]);
      float S = dlt;
#pragma unroll
      for (int ofs = 1; ofs < 64; ofs <<= 1) {
        float v = __shfl_up(S, ofs, 64);
        if (lane >= ofs) S += v;
      }
      float tot = __shfl(S, 63, 64);
      S += carry; carry += tot;
      float corr = 0.f;
#pragma unroll
      for (int nn = 0; nn < 16; nn++) {
        float Cn = Cfp[(size_t)nn * SEQ + t];
        corr = fmaf(Cn * Hn[nn], __expf(A_[nn] * S), corr);
      }
      float gate = b2f(zgp[(size_t)pmap(br, t) * 16 + dsub]);
      float y = corr * gate;
      red[w][lane] = y;
      __syncthreads();
      if (w == 0) {
        float ytot = red[0][lane] + red[1][lane] + red[2][lane] + red[3][lane];
        atomicAdd(srow + omap(br, t), ytot);
      }
      __syncthreads();
    }
  }
}

// ---------------- K8: w_eff[d] = lin_w . out_proj_w[:,d]; zero score_acc ------
__global__ __launch_bounds__(256) void k_weff_init(const ushort_t* __restrict__ opwb,
    const ushort_t* __restrict__ lwb, float* __restrict__ weff, float* __restrict__ sc) {
  int i = blockIdx.x * 256 + threadIdx.x;
  if (i < DI) {
    float s = 0.f;
    for (int o = 0; o < DIMX; o++) s += b2f(lwb[o]) * b2f(opwb[(size_t)o * DI + i]);
    weff[i] = s;
  }
  int j = i - DI;
  if (j >= 0 && j < 2 * SEQ) sc[j] = 0.f;
}

// ---------------- K9: outputs (f32): group interp+sigmoid, individual ---------
__global__ __launch_bounds__(256) void k_out(const float* __restrict__ g0,
    const float* __restrict__ g1, const float* __restrict__ g2,
    const float* __restrict__ sc, const float* __restrict__ lbf,
    float* __restrict__ out) {
  int idx = blockIdx.x * 256 + threadIdx.x;
  if (idx < 3 * SEQ) {
    int j = idx / SEQ, t = idx % SEQ;
    const float* g = (j == 0) ? g0 : (j == 1) ? g1 : g2;
    float pos = t * ((float)(LGS - 1) / (float)(SEQ - 1));
    int i0 = (int)floorf(pos);
    if (i0 < 0) i0 = 0; if (i0 > LGS - 2) i0 = LGS - 2;
    float wt = pos - (float)i0;
    float v = g[i0] * (1.f - wt) + g[i0 + 1] * wt;
    out[idx] = 1.f / (1.f + __expf(-v));
  } else if (idx < 5 * SEQ) {
    float t = sc[idx - 3 * SEQ] + lbf[0];
    out[idx] = 1.f / (1.f + __expf(-t));
  }
}

extern "C" void kernel_launch(void* const* d_in, const int* in_sizes, int n_in,
                              void* d_out, int out_size, void* d_ws, size_t ws_size,
                              hipStream_t stream) {
  char* ws = (char*)d_ws;
  ushort_t* lwb   = (ushort_t*)(ws + OFF_LWB);
  float*    lngf  = (float*)(ws + OFF_LNGF);
  float*    lnbf  = (float*)(ws + OFF_LNBF);
  float*    lbf   = (float*)(ws + OFF_LBF);
  float*    cwf   = (float*)(ws + OFF_CWF);
  float*    cbf   = (float*)(ws + OFF_CBF);
  float*    dtbf  = (float*)(ws + OFF_DTBF);
  float*    alf   = (float*)(ws + OFF_ALF);
  float*    ddf   = (float*)(ws + OFF_DDF);
  float*    weff  = (float*)(ws + OFF_WEFF);
  float*    sc    = (float*)(ws + OFF_SC);
  ushort_t* dtwb  = (ushort_t*)(ws + OFF_DTWB);
  ushort_t* xpwb  = (ushort_t*)(ws + OFF_XPWB);
  ushort_t* opwb  = (ushort_t*)(ws + OFF_OPWB);
  ushort_t* inwb  = (ushort_t*)(ws + OFF_INWB);
  ushort_t* xd    = (ushort_t*)(ws + OFF_XD);
  ushort_t* dltB  = (ushort_t*)(ws + OFF_DLTB);
  ushort_t* xz    = (ushort_t*)(ws + OFF_XZ);
  float*    Bf    = (float*)(ws + OFF_BF);
  float*    Cf    = (float*)(ws + OFF_CF);
  ushort_t* uB    = (ushort_t*)(ws + OFF_UB);
  ushort_t* h     = (ushort_t*)(ws + OFF_H);
  ushort_t* zgB   = (ushort_t*)(ws + OFF_ZGB);
  float*    Hloc  = (float*)(ws + OFF_HLOC);
  float*    Hin   = (float*)(ws + OFF_HIN);
  float*    Stot  = (float*)(ws + OFF_STOT);
  float*    OUT   = (float*)d_out;

  Tab tab;
  int c = 0;
  tab.e[c++] = {d_in[3], inwb, E2 * DIMX, 0};
  tab.e[c++] = {d_in[4], opwb, DIMX * DI, 0};
  tab.e[c++] = {d_in[5], lwb, DIMX, 0};
  for (int br = 0; br < 3; br++) {
    int base = 10 + br * 7;
    tab.e[c++] = {d_in[base + 2], xpwb + (size_t)br * KXP * DI, KXP * DI, 0};
    tab.e[c++] = {d_in[base + 3], dtwb + (size_t)br * DI * DTR, DI * DTR, 0};
  }
  tab.e[c++] = {d_in[1], lngf, DIMX, 1};
  tab.e[c++] = {d_in[2], lnbf, DIMX, 1};
  tab.e[c++] = {d_in[6], lbf, 1, 1};
  for (int br = 0; br < 3; br++) {
    int base = 10 + br * 7;
    tab.e[c++] = {d_in[base + 0], cwf + (size_t)br * DI * 4, DI * 4, 1};
    tab.e[c++] = {d_in[base + 1], cbf + (size_t)br * DI, DI, 1};
    tab.e[c++] = {d_in[base + 4], dtbf + (size_t)br * DI, DI, 1};
    tab.e[c++] = {d_in[base + 5], alf + (size_t)br * DI * NST, DI * NST, 1};
    tab.e[c++] = {d_in[base + 6], ddf + (size_t)br * DI, DI, 1};
  }

  dim3 blk(256);
  k_import<<<dim3(64, c), blk, 0, stream>>>(tab, c);
  k_weff_init<<<44, blk, 0, stream>>>(opwb, lwb, weff, sc);
  k_ln<<<2560, blk, 0, stream>>>((const float*)d_in[0], lngf, lnbf, h);
  k_inproj<<<dim3(80, 16), blk, 0, stream>>>(h, inwb, xz);
  k_conv<<<dim3(80, 16, 6), blk, 0, stream>>>(xz, cwf, cbf, uB);
  k_zg<<<dim3(80, 16, 2), blk, 0, stream>>>(xz, weff, zgB);
  k_xdbl<<<dim3(80, 6), blk, 0, stream>>>(uB, xpwb, xd);
  k_bc<<<dim3(40, 6), blk, 0, stream>>>(xd, Bf, Cf);
  k_delta<<<dim3(40, 8, 6), blk, 0, stream>>>(xd, dtwb, dtbf, dltB);   // xz dead now
  k_scan1<<<3072, blk, 0, stream>>>(dltB, uB, zgB, Bf, Cf, alf, ddf,
                                    sc, Hloc, Stot);
  k_stitch<<<384, blk, 0, stream>>>(Stot, Hloc, alf, Hin);
  k_scan2<<<1536, blk, 0, stream>>>(zgB, dltB, Cf, alf, Hin, sc);
  k_out<<<100, blk, 0, stream>>>((const float*)d_in[7], (const float*)d_in[8],
                                 (const float*)d_in[9], sc, lbf, OUT);
}